// Round 6
// baseline (536.945 us; speedup 1.0000x reference)
//
#include <hip/hip_runtime.h>
#include <math.h>

#define CH 64   // channels (C_IN == C_OUT == 64)

typedef __attribute__((ext_vector_type(8))) short bf16x8;
typedef __attribute__((ext_vector_type(4))) float f32x4;

static __device__ __forceinline__ float bf2f(ushort u) {
    union { unsigned int i; float f; } v; v.i = ((unsigned int)u) << 16; return v.f;
}
static __device__ __forceinline__ ushort f2bf(float f) {
    union { float f; unsigned int i; } v; v.f = f;
    unsigned int lsb = (v.i >> 16) & 1;
    v.i += 0x7fffu + lsb;               // round-to-nearest-even
    return (ushort)(v.i >> 16);
}
static __device__ __forceinline__ unsigned int pack2(float a, float b) {
    return (unsigned int)f2bf(a) | ((unsigned int)f2bf(b) << 16);
}
static __device__ __forceinline__ float lo16(unsigned int u) { return bf2f((ushort)(u & 0xffffu)); }
static __device__ __forceinline__ float hi16(unsigned int u) { return bf2f((ushort)(u >> 16)); }

// ---------------- fused init: atomics | slice-major cast | weight pack ----------------
// XHs layout: [8 slices][N][16ch]  (slices 0-3 = X, 4-7 = H), 32B per (slice,node)

__global__ __launch_bounds__(256) void k_init(
    const int* __restrict__ src, const int* __restrict__ dst,
    const float* __restrict__ w,
    float* __restrict__ deg, int* __restrict__ cnt, int* __restrict__ erank, int E,
    const float4* __restrict__ X4, const float4* __restrict__ H4,
    ushort* __restrict__ XHs, int N,
    const float* __restrict__ Wxz, const float* __restrict__ Whz,
    const float* __restrict__ Wxr, const float* __restrict__ Whr,
    const float* __restrict__ Wxh, const float* __restrict__ Whh,
    ushort* __restrict__ Bp, int bE, int bC)
{
    __shared__ ushort lds[16][128];
    int b = blockIdx.x;
    int tid = threadIdx.x;
    if (b < bE) {
        // degree over src, histogram+rank over dst
        int i = b * 256 + tid;
        if (i < E) {
            atomicAdd(&deg[src[i]], w[i]);
            erank[i] = atomicAdd(&cnt[dst[i]], 1);
        }
    } else if (b < bE + bC) {
        // cast 16 nodes: coalesced f32 reads -> LDS -> slice-major bf16 writes
        int node0 = (b - bE) * 16;
        #pragma unroll
        for (int it = 0; it < 2; ++it) {
            int fi = it * 256 + tid;            // [0,512): 16 nodes x 32 float4
            int nl = fi >> 5, piece = fi & 31;
            int node = node0 + nl;
            if (node < N) {
                float4 v = (piece < 16) ? X4[(size_t)node * 16 + piece]
                                        : H4[(size_t)node * 16 + (piece - 16)];
                ushort4 u;
                u.x = f2bf(v.x); u.y = f2bf(v.y); u.z = f2bf(v.z); u.w = f2bf(v.w);
                int ch4 = (piece < 16) ? piece * 4 : 64 + (piece - 16) * 4;
                *(ushort4*)&lds[nl][ch4] = u;
            }
        }
        __syncthreads();
        {
            int slice = tid >> 5, nl = (tid >> 1) & 15, half = tid & 1;
            int node = node0 + nl;
            if (node < N) {
                *(uint4*)(XHs + ((size_t)slice * N + node) * 16 + half * 8) =
                    *(const uint4*)&lds[nl][slice * 16 + half * 8];
            }
        }
    } else {
        // pack weights: Bp[mtg][ct][lane][e]; mtg: z=0..11, r=12..23, h(x)=24..29, hh=30..35
        // k-slot: k = kt*32 + (lane>>4)*8 + e (consistent A/B convention)
        int mtg = b - bE - bC;
        int ct = tid >> 6;
        int lane = tid & 63;
        const float* W; int m, kt;
        if (mtg < 12)      { int l = mtg;      m = l >> 1; kt = l & 1; W = (m < 3) ? Wxz + m * 4096 : Whz + (m - 3) * 4096; }
        else if (mtg < 24) { int l = mtg - 12; m = l >> 1; kt = l & 1; W = (m < 3) ? Wxr + m * 4096 : Whr + (m - 3) * 4096; }
        else if (mtg < 30) { int l = mtg - 24; m = l >> 1; kt = l & 1; W = Wxh + m * 4096; }
        else               { int l = mtg - 30; m = l >> 1; kt = l & 1; W = Whh + m * 4096; }
        int cout = ct * 16 + (lane & 15);
        ushort* dstp = Bp + ((((mtg * 4) + ct) * 64 + lane) << 3);
        #pragma unroll
        for (int e = 0; e < 8; ++e) {
            int cin = kt * 32 + ((lane >> 4) << 3) + e;
            dstp[e] = f2bf(W[cin * 64 + cout]);
        }
    }
}

// ---------------- 3-phase multi-block scan ----------------

__global__ __launch_bounds__(256) void k_scanA(const int* __restrict__ cnt,
                                               int* __restrict__ rowptr,
                                               int* __restrict__ bsum, int N) {
    __shared__ int ts[256];
    int tid = threadIdx.x;
    int base = blockIdx.x * 2048 + tid * 8;
    int v[8]; int s = 0;
    #pragma unroll
    for (int k = 0; k < 8; ++k) { int i = base + k; v[k] = (i < N) ? cnt[i] : 0; s += v[k]; }
    ts[tid] = s;
    __syncthreads();
    for (int off = 1; off < 256; off <<= 1) {
        int t = (tid >= off) ? ts[tid - off] : 0;
        __syncthreads();
        ts[tid] += t;
        __syncthreads();
    }
    int run = ts[tid] - s;
    #pragma unroll
    for (int k = 0; k < 8; ++k) { int i = base + k; if (i < N) rowptr[i] = run; run += v[k]; }
    if (tid == 255) bsum[blockIdx.x] = ts[255];
}

__global__ void k_scanB(int* __restrict__ bsum, int B) {
    if (threadIdx.x == 0) {
        int acc = 0;
        for (int b = 0; b < B; ++b) { int t = bsum[b]; bsum[b] = acc; acc += t; }
        bsum[B] = acc;
    }
}

__global__ __launch_bounds__(256) void k_scanC(int* __restrict__ rowptr,
                                               const int* __restrict__ bsum,
                                               float* __restrict__ deg, int N, int B) {
    int base = blockIdx.x * 2048 + threadIdx.x * 8;
    int add = bsum[blockIdx.x];
    #pragma unroll
    for (int k = 0; k < 8; ++k) {
        int i = base + k;
        if (i < N) {
            rowptr[i] += add;
            float d = deg[i];
            deg[i] = (d > 0.f) ? rsqrtf(fmaxf(d, 1e-12f)) : 0.f;
        }
    }
    if (blockIdx.x == 0 && threadIdx.x == 0) rowptr[N] = bsum[B];
}

// ---------------- atomic-free scatter: pos = rowptr[dst] + rank ----------------

__global__ __launch_bounds__(256) void k_scatter(const int* __restrict__ src,
                                                 const int* __restrict__ dst,
                                                 const float* __restrict__ w,
                                                 const float* __restrict__ dis,
                                                 const int* __restrict__ rowptr,
                                                 const int* __restrict__ erank,
                                                 int2* __restrict__ emeta, int E) {
    int e = blockIdx.x * 256 + threadIdx.x;
    if (e < E) {
        int d = dst[e], s = src[e];
        int pos = rowptr[d] + erank[e];
        float lw = -dis[s] * w[e] * dis[d];
        emeta[pos] = make_int2(s, __float_as_int(lw));
    }
}

// ---------------- slice-major CSR propagation ----------------
// block: slice = blockIdx % NS (XCD-resident slice), 4 waves = 4 nodes.
// wave: lane = e8*8 + c; 8 edges x 32B coalesced gathers per iteration;
// shfl_xor (8,16,32) reduces across edge groups.

template<int CHEB>
__global__ __launch_bounds__(256) void k_prop(const int* __restrict__ rowptr,
                                              const int2* __restrict__ emeta,
                                              const unsigned int* __restrict__ t,
                                              const unsigned int* __restrict__ t0,
                                              unsigned int* __restrict__ o,
                                              int N, int NS) {
    int s = blockIdx.x % NS;
    int n = (blockIdx.x / NS) * 4 + (threadIdx.x >> 6);
    if (n >= N) return;
    int lane = threadIdx.x & 63;
    int e8 = lane >> 3, c = lane & 7;
    const unsigned int* tb = t + (size_t)s * N * 8;
    int beg = rowptr[n], end = rowptr[n + 1];
    float ax = 0.f, ay = 0.f;
    for (int j0 = beg; j0 < end; j0 += 8) {
        int j = j0 + e8;
        if (j < end) {
            int2 m = emeta[j];
            unsigned int p = tb[(size_t)m.x * 8 + c];
            float l = __int_as_float(m.y);
            ax = fmaf(l, lo16(p), ax);
            ay = fmaf(l, hi16(p), ay);
        }
    }
    #pragma unroll
    for (int mask = 8; mask < 64; mask <<= 1) {
        ax += __shfl_xor(ax, mask, 64);
        ay += __shfl_xor(ay, mask, 64);
    }
    if (e8 == 0) {
        size_t oi = ((size_t)s * N + n) * 8 + c;
        if (CHEB) {
            unsigned int z = t0[oi];
            o[oi] = pack2(2.f * ax - lo16(z), 2.f * ay - hi16(z));
        } else {
            o[oi] = pack2(ax, ay);
        }
    }
}

// ---------------- MFMA GEMM helpers (slice-major A operand) ----------------
// wave computes 32 rows x 64 cols; k-slot: k = kt*32 + (lane>>4)*8 + e
// A load: 8 contiguous bf16 at global channel gch (never crosses a 16-ch slice)

static __device__ __forceinline__ bf16x8 ldA_s(const ushort* __restrict__ base,
                                               int N, int row, int gch) {
    bf16x8 v = {};
    if (row < N)
        v = *(const bf16x8*)(base + ((size_t)(gch >> 4) * N + row) * 16 + (gch & 15));
    return v;
}
static __device__ __forceinline__ bf16x8 ldB(const ushort* __restrict__ bp,
                                             int mt, int ct, int lane) {
    return *(const bf16x8*)(bp + ((((mt * 4) + ct) * 64 + lane) << 3));
}

#define MFMA(a, b, c) __builtin_amdgcn_mfma_f32_16x16x32_bf16(a, b, c, 0, 0, 0)

// ---------------- Pass A: Z(bf16 planar), HR(slice-major), preH(f32 in d_out) ----------------

__global__ __launch_bounds__(256) void k_gA(
    const ushort* __restrict__ XHs, const ushort* __restrict__ T1s, const ushort* __restrict__ T2s,
    const ushort* __restrict__ Bp,
    const float* __restrict__ bxz, const float* __restrict__ bhz,
    const float* __restrict__ bxr, const float* __restrict__ bhr,
    const float* __restrict__ bxh,
    const float* __restrict__ H,
    ushort* __restrict__ Zb, ushort* __restrict__ HRs, float* __restrict__ preH, int N)
{
    int wid = blockIdx.x * 4 + (threadIdx.x >> 6);
    int lane = threadIdx.x & 63;
    int row0 = wid * 32;
    if (row0 >= N) return;

    f32x4 accZ[2][4], accR[2][4], accH[2][4];
    #pragma unroll
    for (int ct = 0; ct < 4; ++ct) {
        int col = ct * 16 + (lane & 15);
        float bz = bxz[col] + bhz[col];
        float br = bxr[col] + bhr[col];
        float bh = bxh[col];
        #pragma unroll
        for (int rt = 0; rt < 2; ++rt) {
            accZ[rt][ct] = (f32x4){bz, bz, bz, bz};
            accR[rt][ct] = (f32x4){br, br, br, br};
            accH[rt][ct] = (f32x4){bh, bh, bh, bh};
        }
    }

    const ushort* bufs[3] = { XHs, T1s, T2s };

    #pragma unroll
    for (int m = 0; m < 6; ++m) {
        const ushort* buf = bufs[m < 3 ? m : m - 3];
        int gofs = (m < 3) ? 0 : 64;
        #pragma unroll
        for (int kt = 0; kt < 2; ++kt) {
            int gch = gofs + kt * 32 + ((lane >> 4) << 3);
            bf16x8 a0 = ldA_s(buf, N, row0 + (lane & 15), gch);
            bf16x8 a1 = ldA_s(buf, N, row0 + 16 + (lane & 15), gch);
            int mt = m * 2 + kt;
            #pragma unroll
            for (int ct = 0; ct < 4; ++ct) {
                bf16x8 bz8 = ldB(Bp, mt, ct, lane);
                accZ[0][ct] = MFMA(a0, bz8, accZ[0][ct]);
                accZ[1][ct] = MFMA(a1, bz8, accZ[1][ct]);
                bf16x8 br8 = ldB(Bp, 12 + mt, ct, lane);
                accR[0][ct] = MFMA(a0, br8, accR[0][ct]);
                accR[1][ct] = MFMA(a1, br8, accR[1][ct]);
                if (m < 3) {
                    bf16x8 bh8 = ldB(Bp, 24 + mt, ct, lane);
                    accH[0][ct] = MFMA(a0, bh8, accH[0][ct]);
                    accH[1][ct] = MFMA(a1, bh8, accH[1][ct]);
                }
            }
        }
    }

    #pragma unroll
    for (int rt = 0; rt < 2; ++rt) {
        #pragma unroll
        for (int ct = 0; ct < 4; ++ct) {
            int col = ct * 16 + (lane & 15);
            #pragma unroll
            for (int r = 0; r < 4; ++r) {
                int row = row0 + rt * 16 + ((lane >> 4) << 2) + r;
                if (row < N) {
                    int o = row * CH + col;
                    float z = 1.f / (1.f + expf(-accZ[rt][ct][r]));
                    float rr = 1.f / (1.f + expf(-accR[rt][ct][r]));
                    float h = H[o];
                    Zb[o] = f2bf(z);
                    HRs[((size_t)ct * N + row) * 16 + (lane & 15)] = f2bf(h * rr);
                    preH[o] = accH[rt][ct][r];
                }
            }
        }
    }
}

// ---------------- Pass B: H_new = Z*H + (1-Z)*tanh(preH + hh-conv) ----------------

__global__ __launch_bounds__(256) void k_gB(
    const ushort* __restrict__ HRs, const ushort* __restrict__ T1r, const ushort* __restrict__ T2r,
    const ushort* __restrict__ Bp, const float* __restrict__ bhh,
    const ushort* __restrict__ Zb, const float* __restrict__ H,
    float* __restrict__ out /* preH on entry */, int N)
{
    int wid = blockIdx.x * 4 + (threadIdx.x >> 6);
    int lane = threadIdx.x & 63;
    int row0 = wid * 32;
    if (row0 >= N) return;

    f32x4 acc[2][4];
    #pragma unroll
    for (int ct = 0; ct < 4; ++ct) {
        int col = ct * 16 + (lane & 15);
        float bh = bhh[col];
        #pragma unroll
        for (int rt = 0; rt < 2; ++rt) acc[rt][ct] = (f32x4){bh, bh, bh, bh};
    }

    const ushort* bufs[3] = { HRs, T1r, T2r };

    #pragma unroll
    for (int m = 0; m < 3; ++m) {
        #pragma unroll
        for (int kt = 0; kt < 2; ++kt) {
            int gch = kt * 32 + ((lane >> 4) << 3);
            bf16x8 a0 = ldA_s(bufs[m], N, row0 + (lane & 15), gch);
            bf16x8 a1 = ldA_s(bufs[m], N, row0 + 16 + (lane & 15), gch);
            int mt = 30 + m * 2 + kt;
            #pragma unroll
            for (int ct = 0; ct < 4; ++ct) {
                bf16x8 b8 = ldB(Bp, mt, ct, lane);
                acc[0][ct] = MFMA(a0, b8, acc[0][ct]);
                acc[1][ct] = MFMA(a1, b8, acc[1][ct]);
            }
        }
    }

    #pragma unroll
    for (int rt = 0; rt < 2; ++rt) {
        #pragma unroll
        for (int ct = 0; ct < 4; ++ct) {
            int col = ct * 16 + (lane & 15);
            #pragma unroll
            for (int r = 0; r < 4; ++r) {
                int row = row0 + rt * 16 + ((lane >> 4) << 2) + r;
                if (row < N) {
                    int o = row * CH + col;
                    float pre = acc[rt][ct][r] + out[o];
                    float z = bf2f(Zb[o]);
                    float h = H[o];
                    out[o] = z * h + (1.f - z) * tanhf(pre);
                }
            }
        }
    }
}

// ---------------- launch ----------------

extern "C" void kernel_launch(void* const* d_in, const int* in_sizes, int n_in,
                              void* d_out, int out_size, void* d_ws, size_t ws_size,
                              hipStream_t stream) {
    const float* X   = (const float*)d_in[0];
    const int*   ei  = (const int*)d_in[1];
    const float* ew  = (const float*)d_in[2];
    const float* H   = (const float*)d_in[3];
    const float* Wxz = (const float*)d_in[4];
    const float* bxz = (const float*)d_in[5];
    const float* Whz = (const float*)d_in[6];
    const float* bhz = (const float*)d_in[7];
    const float* Wxr = (const float*)d_in[8];
    const float* bxr = (const float*)d_in[9];
    const float* Whr = (const float*)d_in[10];
    const float* bhr = (const float*)d_in[11];
    const float* Wxh = (const float*)d_in[12];
    const float* bxh = (const float*)d_in[13];
    const float* Whh = (const float*)d_in[14];
    const float* bhh = (const float*)d_in[15];

    const int N = in_sizes[0] / CH;
    const int E = in_sizes[2];
    const long long NC = (long long)N * CH;

    const int* srcI = ei;
    const int* dstI = ei + E;

    // ---- workspace layout ----
    char* p = (char*)d_ws;
    auto alloc = [&](size_t bytes) { char* r = p; p += (bytes + 255) & ~(size_t)255; return r; };
    int*    rowptr = (int*)alloc((size_t)(N + 1) * 4);
    int2*   emeta  = (int2*)alloc((size_t)E * 8);
    int*    erank  = (int*)alloc((size_t)E * 4);
    float*  deg    = (float*)alloc((size_t)N * 8);      // deg (N) + cnt (N), contiguous
    int*    cnt    = (int*)(deg + N);
    int*    bsum   = (int*)alloc(256 * 4);
    ushort* Bp     = (ushort*)alloc((size_t)36 * 4 * 64 * 8 * 2);
    ushort* XHs    = (ushort*)alloc((size_t)NC * 2 * 2);   // [8][N][16] slice-major X|H
    ushort* T1s    = (ushort*)alloc((size_t)NC * 2 * 2);   // [8][N][16]
    ushort* T2s    = (ushort*)alloc((size_t)NC * 2 * 2);   // [8][N][16]
    ushort* HRs    = (ushort*)alloc((size_t)NC * 2);       // [4][N][16]
    ushort* T1r    = (ushort*)alloc((size_t)NC * 2);       // [4][N][16]
    ushort* T2r    = (ushort*)alloc((size_t)NC * 2);       // [4][N][16]
    ushort* Zb     = (ushort*)alloc((size_t)NC * 2);       // planar
    float*  preH   = (float*)d_out;

    const int bE = (E + 255) / 256;
    const int bC = (N + 15) / 16;                        // cast blocks (16 nodes each)
    const int B  = (N + 2047) / 2048;                    // scan blocks
    const int bP8 = 8 * ((N + 3) / 4);                   // prop blocks, 8 slices
    const int bP4 = 4 * ((N + 3) / 4);                   // prop blocks, 4 slices
    const int nW = (N + 31) / 32;
    const int bG = (nW + 3) / 4;

    // fused init: degree+hist+rank | slice-major cast | pack
    hipMemsetAsync(deg, 0, (size_t)N * 8, stream);
    k_init<<<bE + bC + 36, 256, 0, stream>>>(srcI, dstI, ew, deg, cnt, erank, E,
                                             (const float4*)X, (const float4*)H, XHs, N,
                                             Wxz, Whz, Wxr, Whr, Wxh, Whh, Bp, bE, bC);

    // multi-block scan (+ fused rsqrt)
    k_scanA<<<B, 256, 0, stream>>>(cnt, rowptr, bsum, N);
    k_scanB<<<1, 64, 0, stream>>>(bsum, B);
    k_scanC<<<B, 256, 0, stream>>>(rowptr, bsum, deg, N, B);

    // atomic-free CSR scatter
    k_scatter<<<bE, 256, 0, stream>>>(srcI, dstI, ew, deg, rowptr, erank, emeta, E);

    // Chebyshev bases for X|H (slice-major, XCD-resident slices)
    k_prop<0><<<bP8, 256, 0, stream>>>(rowptr, emeta, (const unsigned int*)XHs,
                                       (const unsigned int*)XHs, (unsigned int*)T1s, N, 8);
    k_prop<1><<<bP8, 256, 0, stream>>>(rowptr, emeta, (const unsigned int*)T1s,
                                       (const unsigned int*)XHs, (unsigned int*)T2s, N, 8);

    // Pass A: Z, H*R, preH
    k_gA<<<bG, 256, 0, stream>>>(XHs, T1s, T2s, Bp,
                                 bxz, bhz, bxr, bhr, bxh,
                                 H, Zb, HRs, preH, N);

    // Chebyshev bases for H*R (4 slices)
    k_prop<0><<<bP4, 256, 0, stream>>>(rowptr, emeta, (const unsigned int*)HRs,
                                       (const unsigned int*)HRs, (unsigned int*)T1r, N, 4);
    k_prop<1><<<bP4, 256, 0, stream>>>(rowptr, emeta, (const unsigned int*)T1r,
                                       (const unsigned int*)HRs, (unsigned int*)T2r, N, 4);

    // Pass B: H_new
    k_gB<<<bG, 256, 0, stream>>>(HRs, T1r, T2r, Bp, bhh, Zb, H, (float*)d_out, N);
}

// Round 7
// 331.694 us; speedup vs baseline: 1.6188x; 1.6188x over previous
//
#include <hip/hip_runtime.h>
#include <math.h>

#define CH 64   // channels (C_IN == C_OUT == 64)

typedef __attribute__((ext_vector_type(8))) short bf16x8;
typedef __attribute__((ext_vector_type(4))) float f32x4;
typedef __attribute__((ext_vector_type(2))) int int2v;

static __device__ __forceinline__ float bf2f(ushort u) {
    union { unsigned int i; float f; } v; v.i = ((unsigned int)u) << 16; return v.f;
}
static __device__ __forceinline__ ushort f2bf(float f) {
    union { float f; unsigned int i; } v; v.f = f;
    unsigned int lsb = (v.i >> 16) & 1;
    v.i += 0x7fffu + lsb;               // round-to-nearest-even
    return (ushort)(v.i >> 16);
}
static __device__ __forceinline__ unsigned int pack2(float a, float b) {
    return (unsigned int)f2bf(a) | ((unsigned int)f2bf(b) << 16);
}
static __device__ __forceinline__ float lo16(unsigned int u) { return bf2f((ushort)(u & 0xffffu)); }
static __device__ __forceinline__ float hi16(unsigned int u) { return bf2f((ushort)(u >> 16)); }

// ---------------- fused init: degree+hist+rank | bf16 cast | weight pack ----------------

__global__ __launch_bounds__(256) void k_init(
    const int* __restrict__ src, const int* __restrict__ dst,
    const float* __restrict__ w,
    float* __restrict__ deg, int* __restrict__ cnt, int* __restrict__ erank, int E,
    const float4* __restrict__ X, const float4* __restrict__ H,
    ushort* __restrict__ XHb, int total4,
    const float* __restrict__ Wxz, const float* __restrict__ Whz,
    const float* __restrict__ Wxr, const float* __restrict__ Whr,
    const float* __restrict__ Wxh, const float* __restrict__ Whh,
    ushort* __restrict__ Bp, int bE, int bC)
{
    int b = blockIdx.x;
    int tid = threadIdx.x;
    if (b < bE) {
        // degree over src, histogram+rank over dst
        int i = b * 256 + tid;
        if (i < E) {
            atomicAdd(&deg[src[i]], w[i]);
            erank[i] = atomicAdd(&cnt[dst[i]], 1);
        }
    } else if (b < bE + bC) {
        // cast X,H -> bf16, interleaved rows [X(64)|H(64)]
        int i = (b - bE) * 256 + tid;
        if (i < total4) {
            float4 x = X[i], h = H[i];
            int node = i >> 4, c4 = i & 15;
            ushort4 xb, hb;
            xb.x = f2bf(x.x); xb.y = f2bf(x.y); xb.z = f2bf(x.z); xb.w = f2bf(x.w);
            hb.x = f2bf(h.x); hb.y = f2bf(h.y); hb.z = f2bf(h.z); hb.w = f2bf(h.w);
            *(ushort4*)(XHb + (size_t)node * 128 + c4 * 4)      = xb;
            *(ushort4*)(XHb + (size_t)node * 128 + 64 + c4 * 4) = hb;
        }
    } else {
        // pack weights: Bp[mtg][ct][lane][e]; mtg: z=0..11, r=12..23, h(x)=24..29, hh=30..35
        // k-slot: k = kt*32 + (lane>>4)*8 + e (consistent A/B convention)
        int mtg = b - bE - bC;
        int ct = tid >> 6;
        int lane = tid & 63;
        const float* W; int m, kt;
        if (mtg < 12)      { int l = mtg;      m = l >> 1; kt = l & 1; W = (m < 3) ? Wxz + m * 4096 : Whz + (m - 3) * 4096; }
        else if (mtg < 24) { int l = mtg - 12; m = l >> 1; kt = l & 1; W = (m < 3) ? Wxr + m * 4096 : Whr + (m - 3) * 4096; }
        else if (mtg < 30) { int l = mtg - 24; m = l >> 1; kt = l & 1; W = Wxh + m * 4096; }
        else               { int l = mtg - 30; m = l >> 1; kt = l & 1; W = Whh + m * 4096; }
        int cout = ct * 16 + (lane & 15);
        ushort* dstp = Bp + ((((mtg * 4) + ct) * 64 + lane) << 3);
        #pragma unroll
        for (int e = 0; e < 8; ++e) {
            int cin = kt * 32 + ((lane >> 4) << 3) + e;
            dstp[e] = f2bf(W[cin * 64 + cout]);
        }
    }
}

// ---------------- 3-phase multi-block scan ----------------

__global__ __launch_bounds__(256) void k_scanA(const int* __restrict__ cnt,
                                               int* __restrict__ rowptr,
                                               int* __restrict__ bsum, int N) {
    __shared__ int ts[256];
    int tid = threadIdx.x;
    int base = blockIdx.x * 2048 + tid * 8;
    int v[8]; int s = 0;
    #pragma unroll
    for (int k = 0; k < 8; ++k) { int i = base + k; v[k] = (i < N) ? cnt[i] : 0; s += v[k]; }
    ts[tid] = s;
    __syncthreads();
    for (int off = 1; off < 256; off <<= 1) {
        int t = (tid >= off) ? ts[tid - off] : 0;
        __syncthreads();
        ts[tid] += t;
        __syncthreads();
    }
    int run = ts[tid] - s;
    #pragma unroll
    for (int k = 0; k < 8; ++k) { int i = base + k; if (i < N) rowptr[i] = run; run += v[k]; }
    if (tid == 255) bsum[blockIdx.x] = ts[255];
}

// wave-parallel scan of block sums (B <= 64)
__global__ void k_scanB(int* __restrict__ bsum, int B) {
    int lane = threadIdx.x;
    int v = (lane < B) ? bsum[lane] : 0;
    int incl = v;
    #pragma unroll
    for (int off = 1; off < 64; off <<= 1) {
        int t = __shfl_up(incl, off, 64);
        if (lane >= off) incl += t;
    }
    if (lane < B) bsum[lane] = incl - v;
    if (lane == B - 1) bsum[B] = incl;
}

__global__ __launch_bounds__(256) void k_scanC(int* __restrict__ rowptr,
                                               const int* __restrict__ bsum,
                                               float* __restrict__ deg, int N, int B) {
    int base = blockIdx.x * 2048 + threadIdx.x * 8;
    int add = bsum[blockIdx.x];
    #pragma unroll
    for (int k = 0; k < 8; ++k) {
        int i = base + k;
        if (i < N) {
            rowptr[i] += add;
            float d = deg[i];
            deg[i] = (d > 0.f) ? rsqrtf(fmaxf(d, 1e-12f)) : 0.f;
        }
    }
    if (blockIdx.x == 0 && threadIdx.x == 0) rowptr[N] = bsum[B];
}

// ---------------- atomic-free scatter: pos = rowptr[dst] + rank ----------------

__global__ __launch_bounds__(256) void k_scatter(const int* __restrict__ src,
                                                 const int* __restrict__ dst,
                                                 const float* __restrict__ w,
                                                 const float* __restrict__ dis,
                                                 const int* __restrict__ rowptr,
                                                 const int* __restrict__ erank,
                                                 int2* __restrict__ emeta, int E) {
    int e = blockIdx.x * 256 + threadIdx.x;
    if (e < E) {
        int d = dst[e], s = src[e];
        int pos = rowptr[d] + erank[e];
        float lw = -dis[s] * w[e] * dis[d];
        emeta[pos] = make_int2(s, __float_as_int(lw));
    }
}

// ---------------- CSR propagation, dual (interleaved X|H rows, 256B/edge) ----------------
// one wave per node; lane = uint = 2 bf16 channels; unroll 8 for MLP

#define DUAL_STEP(mm) { \
    unsigned int p = t[(size_t)(mm).x * 64 + lane]; \
    float l = __int_as_float((mm).y); \
    ax = fmaf(l, lo16(p), ax); ay = fmaf(l, hi16(p), ay); }

__global__ __launch_bounds__(256) void k_prop_dual(const int* __restrict__ rowptr,
                                                   const int2v* __restrict__ emeta,
                                                   const unsigned int* __restrict__ t,
                                                   unsigned int* __restrict__ o, int N) {
    int wid = (blockIdx.x * 256 + threadIdx.x) >> 6;
    int lane = threadIdx.x & 63;
    if (wid >= N) return;
    int beg = rowptr[wid], end = rowptr[wid + 1];
    float ax = 0.f, ay = 0.f;
    int j = beg;
    for (; j + 7 < end; j += 8) {
        int2v m0 = __builtin_nontemporal_load(&emeta[j]);
        int2v m1 = __builtin_nontemporal_load(&emeta[j + 1]);
        int2v m2 = __builtin_nontemporal_load(&emeta[j + 2]);
        int2v m3 = __builtin_nontemporal_load(&emeta[j + 3]);
        int2v m4 = __builtin_nontemporal_load(&emeta[j + 4]);
        int2v m5 = __builtin_nontemporal_load(&emeta[j + 5]);
        int2v m6 = __builtin_nontemporal_load(&emeta[j + 6]);
        int2v m7 = __builtin_nontemporal_load(&emeta[j + 7]);
        DUAL_STEP(m0) DUAL_STEP(m1) DUAL_STEP(m2) DUAL_STEP(m3)
        DUAL_STEP(m4) DUAL_STEP(m5) DUAL_STEP(m6) DUAL_STEP(m7)
    }
    for (; j < end; ++j) {
        int2v m = __builtin_nontemporal_load(&emeta[j]);
        DUAL_STEP(m)
    }
    o[(size_t)wid * 64 + lane] = pack2(ax, ay);
}

__global__ __launch_bounds__(256) void k_prop_dual2(const int* __restrict__ rowptr,
                                                    const int2v* __restrict__ emeta,
                                                    const unsigned int* __restrict__ t,
                                                    const unsigned int* __restrict__ t0,
                                                    unsigned int* __restrict__ o, int N) {
    int wid = (blockIdx.x * 256 + threadIdx.x) >> 6;
    int lane = threadIdx.x & 63;
    if (wid >= N) return;
    int beg = rowptr[wid], end = rowptr[wid + 1];
    float ax = 0.f, ay = 0.f;
    int j = beg;
    for (; j + 7 < end; j += 8) {
        int2v m0 = __builtin_nontemporal_load(&emeta[j]);
        int2v m1 = __builtin_nontemporal_load(&emeta[j + 1]);
        int2v m2 = __builtin_nontemporal_load(&emeta[j + 2]);
        int2v m3 = __builtin_nontemporal_load(&emeta[j + 3]);
        int2v m4 = __builtin_nontemporal_load(&emeta[j + 4]);
        int2v m5 = __builtin_nontemporal_load(&emeta[j + 5]);
        int2v m6 = __builtin_nontemporal_load(&emeta[j + 6]);
        int2v m7 = __builtin_nontemporal_load(&emeta[j + 7]);
        DUAL_STEP(m0) DUAL_STEP(m1) DUAL_STEP(m2) DUAL_STEP(m3)
        DUAL_STEP(m4) DUAL_STEP(m5) DUAL_STEP(m6) DUAL_STEP(m7)
    }
    for (; j < end; ++j) {
        int2v m = __builtin_nontemporal_load(&emeta[j]);
        DUAL_STEP(m)
    }
    size_t oi = (size_t)wid * 64 + lane;
    unsigned int z = t0[oi];
    o[oi] = pack2(2.f * ax - lo16(z), 2.f * ay - hi16(z));
}

// ---------------- CSR propagation, single feature (H*R): 2 nodes/wave ----------------
// 32-lane subgroup per node; lane = uint = 2 bf16 channels (128B/edge); unroll 8

#define HR_STEP(mm) { \
    unsigned int p = t[(size_t)(mm).x * 32 + sl]; \
    float l = __int_as_float((mm).y); \
    ax = fmaf(l, lo16(p), ax); ay = fmaf(l, hi16(p), ay); }

__global__ __launch_bounds__(256) void k_prop1(const int* __restrict__ rowptr,
                                               const int2v* __restrict__ emeta,
                                               const unsigned int* __restrict__ t,
                                               unsigned int* __restrict__ out, int N) {
    int wv = (blockIdx.x * 256 + threadIdx.x) >> 6;
    int lane = threadIdx.x & 63;
    int node = wv * 2 + (lane >> 5);
    int sl = lane & 31;
    if (node >= N) return;
    int beg = rowptr[node], end = rowptr[node + 1];
    float ax = 0.f, ay = 0.f;
    int j = beg;
    for (; j + 7 < end; j += 8) {
        int2v m0 = __builtin_nontemporal_load(&emeta[j]);
        int2v m1 = __builtin_nontemporal_load(&emeta[j + 1]);
        int2v m2 = __builtin_nontemporal_load(&emeta[j + 2]);
        int2v m3 = __builtin_nontemporal_load(&emeta[j + 3]);
        int2v m4 = __builtin_nontemporal_load(&emeta[j + 4]);
        int2v m5 = __builtin_nontemporal_load(&emeta[j + 5]);
        int2v m6 = __builtin_nontemporal_load(&emeta[j + 6]);
        int2v m7 = __builtin_nontemporal_load(&emeta[j + 7]);
        HR_STEP(m0) HR_STEP(m1) HR_STEP(m2) HR_STEP(m3)
        HR_STEP(m4) HR_STEP(m5) HR_STEP(m6) HR_STEP(m7)
    }
    for (; j < end; ++j) {
        int2v m = __builtin_nontemporal_load(&emeta[j]);
        HR_STEP(m)
    }
    out[(size_t)node * 32 + sl] = pack2(ax, ay);
}

__global__ __launch_bounds__(256) void k_prop2(const int* __restrict__ rowptr,
                                               const int2v* __restrict__ emeta,
                                               const unsigned int* __restrict__ t,
                                               const unsigned int* __restrict__ t0,
                                               unsigned int* __restrict__ out, int N) {
    int wv = (blockIdx.x * 256 + threadIdx.x) >> 6;
    int lane = threadIdx.x & 63;
    int node = wv * 2 + (lane >> 5);
    int sl = lane & 31;
    if (node >= N) return;
    int beg = rowptr[node], end = rowptr[node + 1];
    float ax = 0.f, ay = 0.f;
    int j = beg;
    for (; j + 7 < end; j += 8) {
        int2v m0 = __builtin_nontemporal_load(&emeta[j]);
        int2v m1 = __builtin_nontemporal_load(&emeta[j + 1]);
        int2v m2 = __builtin_nontemporal_load(&emeta[j + 2]);
        int2v m3 = __builtin_nontemporal_load(&emeta[j + 3]);
        int2v m4 = __builtin_nontemporal_load(&emeta[j + 4]);
        int2v m5 = __builtin_nontemporal_load(&emeta[j + 5]);
        int2v m6 = __builtin_nontemporal_load(&emeta[j + 6]);
        int2v m7 = __builtin_nontemporal_load(&emeta[j + 7]);
        HR_STEP(m0) HR_STEP(m1) HR_STEP(m2) HR_STEP(m3)
        HR_STEP(m4) HR_STEP(m5) HR_STEP(m6) HR_STEP(m7)
    }
    for (; j < end; ++j) {
        int2v m = __builtin_nontemporal_load(&emeta[j]);
        HR_STEP(m)
    }
    size_t oi = (size_t)node * 32 + sl;
    unsigned int z = t0[oi];
    out[oi] = pack2(2.f * ax - lo16(z), 2.f * ay - hi16(z));
}

// ---------------- MFMA GEMM helpers ----------------
// wave computes 32 rows x 64 cols; k-slot: k = kt*32 + (lane>>4)*8 + e

static __device__ __forceinline__ bf16x8 ldA(const ushort* __restrict__ t, int stride,
                                             int row0, int lane, int kt, int N) {
    int row = row0 + (lane & 15);
    bf16x8 v = {};
    if (row < N) v = *(const bf16x8*)(t + (size_t)row * stride + kt * 32 + ((lane >> 4) << 3));
    return v;
}
static __device__ __forceinline__ bf16x8 ldB(const ushort* __restrict__ bp,
                                             int mt, int ct, int lane) {
    return *(const bf16x8*)(bp + ((((mt * 4) + ct) * 64 + lane) << 3));
}

#define MFMA(a, b, c) __builtin_amdgcn_mfma_f32_16x16x32_bf16(a, b, c, 0, 0, 0)

// ---------------- Pass A: Z(bf16), HR(bf16), preH(bf16) ----------------

__global__ __launch_bounds__(256) void k_gA(
    const ushort* __restrict__ XHb, const ushort* __restrict__ T1xh, const ushort* __restrict__ T2xh,
    const ushort* __restrict__ Bp,
    const float* __restrict__ bxz, const float* __restrict__ bhz,
    const float* __restrict__ bxr, const float* __restrict__ bhr,
    const float* __restrict__ bxh,
    const float* __restrict__ H,
    ushort* __restrict__ Zb, ushort* __restrict__ HRb, ushort* __restrict__ preHb, int N)
{
    int wid = blockIdx.x * 4 + (threadIdx.x >> 6);
    int lane = threadIdx.x & 63;
    int row0 = wid * 32;
    if (row0 >= N) return;

    f32x4 accZ[2][4], accR[2][4], accH[2][4];
    #pragma unroll
    for (int ct = 0; ct < 4; ++ct) {
        int col = ct * 16 + (lane & 15);
        float bz = bxz[col] + bhz[col];
        float br = bxr[col] + bhr[col];
        float bh = bxh[col];
        #pragma unroll
        for (int rt = 0; rt < 2; ++rt) {
            accZ[rt][ct] = (f32x4){bz, bz, bz, bz};
            accR[rt][ct] = (f32x4){br, br, br, br};
            accH[rt][ct] = (f32x4){bh, bh, bh, bh};
        }
    }

    const ushort* ins[6] = { XHb, T1xh, T2xh, XHb + 64, T1xh + 64, T2xh + 64 };

    #pragma unroll
    for (int m = 0; m < 6; ++m) {
        #pragma unroll
        for (int kt = 0; kt < 2; ++kt) {
            bf16x8 a0 = ldA(ins[m], 128, row0,      lane, kt, N);
            bf16x8 a1 = ldA(ins[m], 128, row0 + 16, lane, kt, N);
            int mt = m * 2 + kt;
            #pragma unroll
            for (int ct = 0; ct < 4; ++ct) {
                bf16x8 bz8 = ldB(Bp, mt, ct, lane);
                accZ[0][ct] = MFMA(a0, bz8, accZ[0][ct]);
                accZ[1][ct] = MFMA(a1, bz8, accZ[1][ct]);
                bf16x8 br8 = ldB(Bp, 12 + mt, ct, lane);
                accR[0][ct] = MFMA(a0, br8, accR[0][ct]);
                accR[1][ct] = MFMA(a1, br8, accR[1][ct]);
                if (m < 3) {
                    bf16x8 bh8 = ldB(Bp, 24 + mt, ct, lane);
                    accH[0][ct] = MFMA(a0, bh8, accH[0][ct]);
                    accH[1][ct] = MFMA(a1, bh8, accH[1][ct]);
                }
            }
        }
    }

    #pragma unroll
    for (int rt = 0; rt < 2; ++rt) {
        #pragma unroll
        for (int ct = 0; ct < 4; ++ct) {
            int col = ct * 16 + (lane & 15);
            #pragma unroll
            for (int r = 0; r < 4; ++r) {
                int row = row0 + rt * 16 + ((lane >> 4) << 2) + r;
                if (row < N) {
                    int o = row * CH + col;
                    float z = 1.f / (1.f + expf(-accZ[rt][ct][r]));
                    float rr = 1.f / (1.f + expf(-accR[rt][ct][r]));
                    float h = H[o];
                    Zb[o] = f2bf(z);
                    HRb[o] = f2bf(h * rr);
                    preHb[o] = f2bf(accH[rt][ct][r]);
                }
            }
        }
    }
}

// ---------------- Pass B: H_new = Z*H + (1-Z)*tanh(preH + hh-conv) ----------------

__global__ __launch_bounds__(256) void k_gB(
    const ushort* __restrict__ HRb, const ushort* __restrict__ T1, const ushort* __restrict__ T2,
    const ushort* __restrict__ Bp, const float* __restrict__ bhh,
    const ushort* __restrict__ Zb, const float* __restrict__ H,
    const ushort* __restrict__ preHb, float* __restrict__ out, int N)
{
    int wid = blockIdx.x * 4 + (threadIdx.x >> 6);
    int lane = threadIdx.x & 63;
    int row0 = wid * 32;
    if (row0 >= N) return;

    f32x4 acc[2][4];
    #pragma unroll
    for (int ct = 0; ct < 4; ++ct) {
        int col = ct * 16 + (lane & 15);
        float bh = bhh[col];
        #pragma unroll
        for (int rt = 0; rt < 2; ++rt) acc[rt][ct] = (f32x4){bh, bh, bh, bh};
    }

    const ushort* ins[3] = { HRb, T1, T2 };

    #pragma unroll
    for (int m = 0; m < 3; ++m) {
        #pragma unroll
        for (int kt = 0; kt < 2; ++kt) {
            bf16x8 a0 = ldA(ins[m], 64, row0,      lane, kt, N);
            bf16x8 a1 = ldA(ins[m], 64, row0 + 16, lane, kt, N);
            int mt = 30 + m * 2 + kt;
            #pragma unroll
            for (int ct = 0; ct < 4; ++ct) {
                bf16x8 b8 = ldB(Bp, mt, ct, lane);
                acc[0][ct] = MFMA(a0, b8, acc[0][ct]);
                acc[1][ct] = MFMA(a1, b8, acc[1][ct]);
            }
        }
    }

    #pragma unroll
    for (int rt = 0; rt < 2; ++rt) {
        #pragma unroll
        for (int ct = 0; ct < 4; ++ct) {
            int col = ct * 16 + (lane & 15);
            #pragma unroll
            for (int r = 0; r < 4; ++r) {
                int row = row0 + rt * 16 + ((lane >> 4) << 2) + r;
                if (row < N) {
                    int o = row * CH + col;
                    float pre = acc[rt][ct][r] + bf2f(preHb[o]);
                    float z = bf2f(Zb[o]);
                    float h = H[o];
                    out[o] = z * h + (1.f - z) * tanhf(pre);
                }
            }
        }
    }
}

// ---------------- launch ----------------

extern "C" void kernel_launch(void* const* d_in, const int* in_sizes, int n_in,
                              void* d_out, int out_size, void* d_ws, size_t ws_size,
                              hipStream_t stream) {
    const float* X   = (const float*)d_in[0];
    const int*   ei  = (const int*)d_in[1];
    const float* ew  = (const float*)d_in[2];
    const float* H   = (const float*)d_in[3];
    const float* Wxz = (const float*)d_in[4];
    const float* bxz = (const float*)d_in[5];
    const float* Whz = (const float*)d_in[6];
    const float* bhz = (const float*)d_in[7];
    const float* Wxr = (const float*)d_in[8];
    const float* bxr = (const float*)d_in[9];
    const float* Whr = (const float*)d_in[10];
    const float* bhr = (const float*)d_in[11];
    const float* Wxh = (const float*)d_in[12];
    const float* bxh = (const float*)d_in[13];
    const float* Whh = (const float*)d_in[14];
    const float* bhh = (const float*)d_in[15];

    const int N = in_sizes[0] / CH;
    const int E = in_sizes[2];
    const long long NC = (long long)N * CH;

    const int* srcI = ei;
    const int* dstI = ei + E;

    // ---- workspace layout ----
    char* p = (char*)d_ws;
    auto alloc = [&](size_t bytes) { char* r = p; p += (bytes + 255) & ~(size_t)255; return r; };
    int*    rowptr = (int*)alloc((size_t)(N + 1) * 4);
    int2*   emeta  = (int2*)alloc((size_t)E * 8);
    int*    erank  = (int*)alloc((size_t)E * 4);
    float*  deg    = (float*)alloc((size_t)N * 8);      // deg (N) + cnt (N), contiguous
    int*    cnt    = (int*)(deg + N);
    int*    bsum   = (int*)alloc(256 * 4);
    ushort* Bp     = (ushort*)alloc((size_t)36 * 4 * 64 * 8 * 2);
    ushort* XHb    = (ushort*)alloc((size_t)NC * 2 * 2);   // interleaved X|H [N][128]
    ushort* T1xh   = (ushort*)alloc((size_t)NC * 2 * 2);
    ushort* T2xh   = (ushort*)alloc((size_t)NC * 2 * 2);
    ushort* HRb    = (ushort*)alloc((size_t)NC * 2);       // planar [N][64]
    ushort* T1r    = (ushort*)alloc((size_t)NC * 2);
    ushort* T2r    = (ushort*)alloc((size_t)NC * 2);
    ushort* Zb     = (ushort*)alloc((size_t)NC * 2);
    ushort* preHb  = (ushort*)alloc((size_t)NC * 2);

    const int total4 = (int)(NC / 4);
    const int bE = (E + 255) / 256;
    const int bC = (total4 + 255) / 256;
    const int B  = (N + 2047) / 2048;                    // scan blocks (<=64)
    const int bW = (int)((N * 64 + 255) / 256);          // one wave per node
    const int bW2 = (int)((((N + 1) / 2) * 64 + 255) / 256); // 2 nodes per wave
    const int nW = (N + 31) / 32;
    const int bG = (nW + 3) / 4;

    // fused init: degree+hist+rank | cast | pack
    hipMemsetAsync(deg, 0, (size_t)N * 8, stream);
    k_init<<<bE + bC + 36, 256, 0, stream>>>(srcI, dstI, ew, deg, cnt, erank, E,
                                             (const float4*)X, (const float4*)H, XHb, total4,
                                             Wxz, Whz, Wxr, Whr, Wxh, Whh, Bp, bE, bC);

    // multi-block scan (+ fused rsqrt)
    k_scanA<<<B, 256, 0, stream>>>(cnt, rowptr, bsum, N);
    k_scanB<<<1, 64, 0, stream>>>(bsum, B);
    k_scanC<<<B, 256, 0, stream>>>(rowptr, bsum, deg, N, B);

    // atomic-free CSR scatter
    k_scatter<<<bE, 256, 0, stream>>>(srcI, dstI, ew, deg, rowptr, erank, emeta, E);

    // Chebyshev bases for X and H (fused, interleaved)
    k_prop_dual <<<bW, 256, 0, stream>>>(rowptr, (const int2v*)emeta, (const unsigned int*)XHb,
                                         (unsigned int*)T1xh, N);
    k_prop_dual2<<<bW, 256, 0, stream>>>(rowptr, (const int2v*)emeta, (const unsigned int*)T1xh,
                                         (const unsigned int*)XHb, (unsigned int*)T2xh, N);

    // Pass A: Z, H*R, preH
    k_gA<<<bG, 256, 0, stream>>>(XHb, T1xh, T2xh, Bp,
                                 bxz, bhz, bxr, bhr, bxh,
                                 H, Zb, HRb, preHb, N);

    // Chebyshev bases for H*R (2 nodes/wave)
    k_prop1<<<bW2, 256, 0, stream>>>(rowptr, (const int2v*)emeta, (const unsigned int*)HRb,
                                     (unsigned int*)T1r, N);
    k_prop2<<<bW2, 256, 0, stream>>>(rowptr, (const int2v*)emeta, (const unsigned int*)T1r,
                                     (const unsigned int*)HRb, (unsigned int*)T2r, N);

    // Pass B: H_new
    k_gB<<<bG, 256, 0, stream>>>(HRb, T1r, T2r, Bp, bhh, Zb, H, preHb, (float*)d_out, N);
}

// Round 8
// 293.537 us; speedup vs baseline: 1.8292x; 1.1300x over previous
//
#include <hip/hip_runtime.h>
#include <math.h>

#define CH 64   // channels (C_IN == C_OUT == 64)

typedef __attribute__((ext_vector_type(8))) short bf16x8;
typedef __attribute__((ext_vector_type(4))) float f32x4;

static __device__ __forceinline__ float bf2f(ushort u) {
    union { unsigned int i; float f; } v; v.i = ((unsigned int)u) << 16; return v.f;
}
static __device__ __forceinline__ ushort f2bf(float f) {
    union { float f; unsigned int i; } v; v.f = f;
    unsigned int lsb = (v.i >> 16) & 1;
    v.i += 0x7fffu + lsb;               // round-to-nearest-even
    return (ushort)(v.i >> 16);
}
static __device__ __forceinline__ unsigned int pack2(float a, float b) {
    return (unsigned int)f2bf(a) | ((unsigned int)f2bf(b) << 16);
}
static __device__ __forceinline__ float lo16(unsigned int u) { return bf2f((ushort)(u & 0xffffu)); }
static __device__ __forceinline__ float hi16(unsigned int u) { return bf2f((ushort)(u >> 16)); }

// ---------------- fused init: degree+hist+rank | bf16 cast | weight pack ----------------

__global__ __launch_bounds__(256) void k_init(
    const int* __restrict__ src, const int* __restrict__ dst,
    const float* __restrict__ w,
    float* __restrict__ deg, int* __restrict__ cnt, int* __restrict__ erank, int E,
    const float4* __restrict__ X, const float4* __restrict__ H,
    ushort* __restrict__ XHb, int total4,
    const float* __restrict__ Wxz, const float* __restrict__ Whz,
    const float* __restrict__ Wxr, const float* __restrict__ Whr,
    const float* __restrict__ Wxh, const float* __restrict__ Whh,
    ushort* __restrict__ Bp, int bE, int bC)
{
    int b = blockIdx.x;
    int tid = threadIdx.x;
    if (b < bE) {
        // degree over src, histogram+rank over dst
        int i = b * 256 + tid;
        if (i < E) {
            atomicAdd(&deg[src[i]], w[i]);
            erank[i] = atomicAdd(&cnt[dst[i]], 1);
        }
    } else if (b < bE + bC) {
        // cast X,H -> bf16, interleaved rows [X(64)|H(64)]
        int i = (b - bE) * 256 + tid;
        if (i < total4) {
            float4 x = X[i], h = H[i];
            int node = i >> 4, c4 = i & 15;
            ushort4 xb, hb;
            xb.x = f2bf(x.x); xb.y = f2bf(x.y); xb.z = f2bf(x.z); xb.w = f2bf(x.w);
            hb.x = f2bf(h.x); hb.y = f2bf(h.y); hb.z = f2bf(h.z); hb.w = f2bf(h.w);
            *(ushort4*)(XHb + (size_t)node * 128 + c4 * 4)      = xb;
            *(ushort4*)(XHb + (size_t)node * 128 + 64 + c4 * 4) = hb;
        }
    } else {
        // pack weights: Bp[mtg][ct][lane][e]; mtg: z=0..11, r=12..23, h(x)=24..29, hh=30..35
        // k-slot: k = kt*32 + (lane>>4)*8 + e (consistent A/B convention)
        int mtg = b - bE - bC;
        int ct = tid >> 6;
        int lane = tid & 63;
        const float* W; int m, kt;
        if (mtg < 12)      { int l = mtg;      m = l >> 1; kt = l & 1; W = (m < 3) ? Wxz + m * 4096 : Whz + (m - 3) * 4096; }
        else if (mtg < 24) { int l = mtg - 12; m = l >> 1; kt = l & 1; W = (m < 3) ? Wxr + m * 4096 : Whr + (m - 3) * 4096; }
        else if (mtg < 30) { int l = mtg - 24; m = l >> 1; kt = l & 1; W = Wxh + m * 4096; }
        else               { int l = mtg - 30; m = l >> 1; kt = l & 1; W = Whh + m * 4096; }
        int cout = ct * 16 + (lane & 15);
        ushort* dstp = Bp + ((((mtg * 4) + ct) * 64 + lane) << 3);
        #pragma unroll
        for (int e = 0; e < 8; ++e) {
            int cin = kt * 32 + ((lane >> 4) << 3) + e;
            dstp[e] = f2bf(W[cin * 64 + cout]);
        }
    }
}

// ---------------- 3-phase multi-block scan ----------------

__global__ __launch_bounds__(256) void k_scanA(const int* __restrict__ cnt,
                                               int* __restrict__ rowptr,
                                               int* __restrict__ bsum, int N) {
    __shared__ int ts[256];
    int tid = threadIdx.x;
    int base = blockIdx.x * 2048 + tid * 8;
    int v[8]; int s = 0;
    #pragma unroll
    for (int k = 0; k < 8; ++k) { int i = base + k; v[k] = (i < N) ? cnt[i] : 0; s += v[k]; }
    ts[tid] = s;
    __syncthreads();
    for (int off = 1; off < 256; off <<= 1) {
        int t = (tid >= off) ? ts[tid - off] : 0;
        __syncthreads();
        ts[tid] += t;
        __syncthreads();
    }
    int run = ts[tid] - s;
    #pragma unroll
    for (int k = 0; k < 8; ++k) { int i = base + k; if (i < N) rowptr[i] = run; run += v[k]; }
    if (tid == 255) bsum[blockIdx.x] = ts[255];
}

// wave-parallel scan of block sums (B <= 64)
__global__ void k_scanB(int* __restrict__ bsum, int B) {
    int lane = threadIdx.x;
    int v = (lane < B) ? bsum[lane] : 0;
    int incl = v;
    #pragma unroll
    for (int off = 1; off < 64; off <<= 1) {
        int t = __shfl_up(incl, off, 64);
        if (lane >= off) incl += t;
    }
    if (lane < B) bsum[lane] = incl - v;
    if (lane == B - 1) bsum[B] = incl;
}

__global__ __launch_bounds__(256) void k_scanC(int* __restrict__ rowptr,
                                               const int* __restrict__ bsum,
                                               float* __restrict__ deg, int N, int B) {
    int base = blockIdx.x * 2048 + threadIdx.x * 8;
    int add = bsum[blockIdx.x];
    #pragma unroll
    for (int k = 0; k < 8; ++k) {
        int i = base + k;
        if (i < N) {
            rowptr[i] += add;
            float d = deg[i];
            deg[i] = (d > 0.f) ? rsqrtf(fmaxf(d, 1e-12f)) : 0.f;
        }
    }
    if (blockIdx.x == 0 && threadIdx.x == 0) rowptr[N] = bsum[B];
}

// ---------------- atomic-free scatter: pos = rowptr[dst] + rank ----------------

__global__ __launch_bounds__(256) void k_scatter(const int* __restrict__ src,
                                                 const int* __restrict__ dst,
                                                 const float* __restrict__ w,
                                                 const float* __restrict__ dis,
                                                 const int* __restrict__ rowptr,
                                                 const int* __restrict__ erank,
                                                 int2* __restrict__ emeta, int E) {
    int e = blockIdx.x * 256 + threadIdx.x;
    if (e < E) {
        int d = dst[e], s = src[e];
        int pos = rowptr[d] + erank[e];
        float lw = -dis[s] * w[e] * dis[d];
        emeta[pos] = make_int2(s, __float_as_int(lw));
    }
}

// ---------------- CSR propagation, dual (interleaved X|H rows, 256B/edge) ----------------
// one wave per node; lane = uint = 2 bf16 channels; unroll 4 (round-5 proven form)

__global__ __launch_bounds__(256) void k_prop_dual(const int* __restrict__ rowptr,
                                                   const int2* __restrict__ emeta,
                                                   const unsigned int* __restrict__ t,
                                                   unsigned int* __restrict__ o, int N) {
    int wid = (blockIdx.x * 256 + threadIdx.x) >> 6;
    int lane = threadIdx.x & 63;
    if (wid >= N) return;
    int beg = rowptr[wid], end = rowptr[wid + 1];
    float ax = 0.f, ay = 0.f;
    int j = beg;
    for (; j + 3 < end; j += 4) {
        int2 m0 = emeta[j], m1 = emeta[j + 1], m2 = emeta[j + 2], m3 = emeta[j + 3];
        unsigned int p0 = t[(size_t)m0.x * 64 + lane];
        unsigned int p1 = t[(size_t)m1.x * 64 + lane];
        unsigned int p2 = t[(size_t)m2.x * 64 + lane];
        unsigned int p3 = t[(size_t)m3.x * 64 + lane];
        float l0 = __int_as_float(m0.y), l1 = __int_as_float(m1.y);
        float l2 = __int_as_float(m2.y), l3 = __int_as_float(m3.y);
        ax = fmaf(l0, lo16(p0), ax); ay = fmaf(l0, hi16(p0), ay);
        ax = fmaf(l1, lo16(p1), ax); ay = fmaf(l1, hi16(p1), ay);
        ax = fmaf(l2, lo16(p2), ax); ay = fmaf(l2, hi16(p2), ay);
        ax = fmaf(l3, lo16(p3), ax); ay = fmaf(l3, hi16(p3), ay);
    }
    for (; j < end; ++j) {
        int2 m = emeta[j];
        unsigned int p = t[(size_t)m.x * 64 + lane];
        float l = __int_as_float(m.y);
        ax = fmaf(l, lo16(p), ax); ay = fmaf(l, hi16(p), ay);
    }
    o[(size_t)wid * 64 + lane] = pack2(ax, ay);
}

__global__ __launch_bounds__(256) void k_prop_dual2(const int* __restrict__ rowptr,
                                                    const int2* __restrict__ emeta,
                                                    const unsigned int* __restrict__ t,
                                                    const unsigned int* __restrict__ t0,
                                                    unsigned int* __restrict__ o, int N) {
    int wid = (blockIdx.x * 256 + threadIdx.x) >> 6;
    int lane = threadIdx.x & 63;
    if (wid >= N) return;
    int beg = rowptr[wid], end = rowptr[wid + 1];
    float ax = 0.f, ay = 0.f;
    int j = beg;
    for (; j + 3 < end; j += 4) {
        int2 m0 = emeta[j], m1 = emeta[j + 1], m2 = emeta[j + 2], m3 = emeta[j + 3];
        unsigned int p0 = t[(size_t)m0.x * 64 + lane];
        unsigned int p1 = t[(size_t)m1.x * 64 + lane];
        unsigned int p2 = t[(size_t)m2.x * 64 + lane];
        unsigned int p3 = t[(size_t)m3.x * 64 + lane];
        float l0 = __int_as_float(m0.y), l1 = __int_as_float(m1.y);
        float l2 = __int_as_float(m2.y), l3 = __int_as_float(m3.y);
        ax = fmaf(l0, lo16(p0), ax); ay = fmaf(l0, hi16(p0), ay);
        ax = fmaf(l1, lo16(p1), ax); ay = fmaf(l1, hi16(p1), ay);
        ax = fmaf(l2, lo16(p2), ax); ay = fmaf(l2, hi16(p2), ay);
        ax = fmaf(l3, lo16(p3), ax); ay = fmaf(l3, hi16(p3), ay);
    }
    for (; j < end; ++j) {
        int2 m = emeta[j];
        unsigned int p = t[(size_t)m.x * 64 + lane];
        float l = __int_as_float(m.y);
        ax = fmaf(l, lo16(p), ax); ay = fmaf(l, hi16(p), ay);
    }
    size_t oi = (size_t)wid * 64 + lane;
    unsigned int z = t0[oi];
    o[oi] = pack2(2.f * ax - lo16(z), 2.f * ay - hi16(z));
}

// ---------------- CSR propagation, single feature (H*R): 2 nodes/wave ----------------
// 32-lane subgroup per node; lane = uint = 2 bf16 channels (128B/edge); unroll 4

__global__ __launch_bounds__(256) void k_prop1(const int* __restrict__ rowptr,
                                               const int2* __restrict__ emeta,
                                               const unsigned int* __restrict__ t,
                                               unsigned int* __restrict__ out, int N) {
    int wv = (blockIdx.x * 256 + threadIdx.x) >> 6;
    int lane = threadIdx.x & 63;
    int node = wv * 2 + (lane >> 5);
    int sl = lane & 31;
    if (node >= N) return;
    int beg = rowptr[node], end = rowptr[node + 1];
    float ax = 0.f, ay = 0.f;
    int j = beg;
    for (; j + 3 < end; j += 4) {
        int2 m0 = emeta[j], m1 = emeta[j + 1], m2 = emeta[j + 2], m3 = emeta[j + 3];
        unsigned int p0 = t[(size_t)m0.x * 32 + sl];
        unsigned int p1 = t[(size_t)m1.x * 32 + sl];
        unsigned int p2 = t[(size_t)m2.x * 32 + sl];
        unsigned int p3 = t[(size_t)m3.x * 32 + sl];
        float l0 = __int_as_float(m0.y), l1 = __int_as_float(m1.y);
        float l2 = __int_as_float(m2.y), l3 = __int_as_float(m3.y);
        ax = fmaf(l0, lo16(p0), ax); ay = fmaf(l0, hi16(p0), ay);
        ax = fmaf(l1, lo16(p1), ax); ay = fmaf(l1, hi16(p1), ay);
        ax = fmaf(l2, lo16(p2), ax); ay = fmaf(l2, hi16(p2), ay);
        ax = fmaf(l3, lo16(p3), ax); ay = fmaf(l3, hi16(p3), ay);
    }
    for (; j < end; ++j) {
        int2 m = emeta[j];
        unsigned int p = t[(size_t)m.x * 32 + sl];
        float l = __int_as_float(m.y);
        ax = fmaf(l, lo16(p), ax); ay = fmaf(l, hi16(p), ay);
    }
    out[(size_t)node * 32 + sl] = pack2(ax, ay);
}

__global__ __launch_bounds__(256) void k_prop2(const int* __restrict__ rowptr,
                                               const int2* __restrict__ emeta,
                                               const unsigned int* __restrict__ t,
                                               const unsigned int* __restrict__ t0,
                                               unsigned int* __restrict__ out, int N) {
    int wv = (blockIdx.x * 256 + threadIdx.x) >> 6;
    int lane = threadIdx.x & 63;
    int node = wv * 2 + (lane >> 5);
    int sl = lane & 31;
    if (node >= N) return;
    int beg = rowptr[node], end = rowptr[node + 1];
    float ax = 0.f, ay = 0.f;
    int j = beg;
    for (; j + 3 < end; j += 4) {
        int2 m0 = emeta[j], m1 = emeta[j + 1], m2 = emeta[j + 2], m3 = emeta[j + 3];
        unsigned int p0 = t[(size_t)m0.x * 32 + sl];
        unsigned int p1 = t[(size_t)m1.x * 32 + sl];
        unsigned int p2 = t[(size_t)m2.x * 32 + sl];
        unsigned int p3 = t[(size_t)m3.x * 32 + sl];
        float l0 = __int_as_float(m0.y), l1 = __int_as_float(m1.y);
        float l2 = __int_as_float(m2.y), l3 = __int_as_float(m3.y);
        ax = fmaf(l0, lo16(p0), ax); ay = fmaf(l0, hi16(p0), ay);
        ax = fmaf(l1, lo16(p1), ax); ay = fmaf(l1, hi16(p1), ay);
        ax = fmaf(l2, lo16(p2), ax); ay = fmaf(l2, hi16(p2), ay);
        ax = fmaf(l3, lo16(p3), ax); ay = fmaf(l3, hi16(p3), ay);
    }
    for (; j < end; ++j) {
        int2 m = emeta[j];
        unsigned int p = t[(size_t)m.x * 32 + sl];
        float l = __int_as_float(m.y);
        ax = fmaf(l, lo16(p), ax); ay = fmaf(l, hi16(p), ay);
    }
    size_t oi = (size_t)node * 32 + sl;
    unsigned int z = t0[oi];
    out[oi] = pack2(2.f * ax - lo16(z), 2.f * ay - hi16(z));
}

// ---------------- MFMA GEMM helpers ----------------
// wave computes 32 rows x 64 cols; k-slot: k = kt*32 + (lane>>4)*8 + e

static __device__ __forceinline__ bf16x8 ldA(const ushort* __restrict__ t, int stride,
                                             int row0, int lane, int kt, int N) {
    int row = row0 + (lane & 15);
    bf16x8 v = {};
    if (row < N) v = *(const bf16x8*)(t + (size_t)row * stride + kt * 32 + ((lane >> 4) << 3));
    return v;
}
static __device__ __forceinline__ bf16x8 ldB(const ushort* __restrict__ bp,
                                             int mt, int ct, int lane) {
    return *(const bf16x8*)(bp + ((((mt * 4) + ct) * 64 + lane) << 3));
}

#define MFMA(a, b, c) __builtin_amdgcn_mfma_f32_16x16x32_bf16(a, b, c, 0, 0, 0)

// ---------------- Pass A: Z(bf16), HR(bf16), preH(bf16) ----------------

__global__ __launch_bounds__(256) void k_gA(
    const ushort* __restrict__ XHb, const ushort* __restrict__ T1xh, const ushort* __restrict__ T2xh,
    const ushort* __restrict__ Bp,
    const float* __restrict__ bxz, const float* __restrict__ bhz,
    const float* __restrict__ bxr, const float* __restrict__ bhr,
    const float* __restrict__ bxh,
    const float* __restrict__ H,
    ushort* __restrict__ Zb, ushort* __restrict__ HRb, ushort* __restrict__ preHb, int N)
{
    int wid = blockIdx.x * 4 + (threadIdx.x >> 6);
    int lane = threadIdx.x & 63;
    int row0 = wid * 32;
    if (row0 >= N) return;

    f32x4 accZ[2][4], accR[2][4], accH[2][4];
    #pragma unroll
    for (int ct = 0; ct < 4; ++ct) {
        int col = ct * 16 + (lane & 15);
        float bz = bxz[col] + bhz[col];
        float br = bxr[col] + bhr[col];
        float bh = bxh[col];
        #pragma unroll
        for (int rt = 0; rt < 2; ++rt) {
            accZ[rt][ct] = (f32x4){bz, bz, bz, bz};
            accR[rt][ct] = (f32x4){br, br, br, br};
            accH[rt][ct] = (f32x4){bh, bh, bh, bh};
        }
    }

    const ushort* ins[6] = { XHb, T1xh, T2xh, XHb + 64, T1xh + 64, T2xh + 64 };

    #pragma unroll
    for (int m = 0; m < 6; ++m) {
        #pragma unroll
        for (int kt = 0; kt < 2; ++kt) {
            bf16x8 a0 = ldA(ins[m], 128, row0,      lane, kt, N);
            bf16x8 a1 = ldA(ins[m], 128, row0 + 16, lane, kt, N);
            int mt = m * 2 + kt;
            #pragma unroll
            for (int ct = 0; ct < 4; ++ct) {
                bf16x8 bz8 = ldB(Bp, mt, ct, lane);
                accZ[0][ct] = MFMA(a0, bz8, accZ[0][ct]);
                accZ[1][ct] = MFMA(a1, bz8, accZ[1][ct]);
                bf16x8 br8 = ldB(Bp, 12 + mt, ct, lane);
                accR[0][ct] = MFMA(a0, br8, accR[0][ct]);
                accR[1][ct] = MFMA(a1, br8, accR[1][ct]);
                if (m < 3) {
                    bf16x8 bh8 = ldB(Bp, 24 + mt, ct, lane);
                    accH[0][ct] = MFMA(a0, bh8, accH[0][ct]);
                    accH[1][ct] = MFMA(a1, bh8, accH[1][ct]);
                }
            }
        }
    }

    #pragma unroll
    for (int rt = 0; rt < 2; ++rt) {
        #pragma unroll
        for (int ct = 0; ct < 4; ++ct) {
            int col = ct * 16 + (lane & 15);
            #pragma unroll
            for (int r = 0; r < 4; ++r) {
                int row = row0 + rt * 16 + ((lane >> 4) << 2) + r;
                if (row < N) {
                    int o = row * CH + col;
                    float z = 1.f / (1.f + expf(-accZ[rt][ct][r]));
                    float rr = 1.f / (1.f + expf(-accR[rt][ct][r]));
                    float h = H[o];
                    Zb[o] = f2bf(z);
                    HRb[o] = f2bf(h * rr);
                    preHb[o] = f2bf(accH[rt][ct][r]);
                }
            }
        }
    }
}

// ---------------- Pass B: H_new = Z*H + (1-Z)*tanh(preH + hh-conv) ----------------

__global__ __launch_bounds__(256) void k_gB(
    const ushort* __restrict__ HRb, const ushort* __restrict__ T1, const ushort* __restrict__ T2,
    const ushort* __restrict__ Bp, const float* __restrict__ bhh,
    const ushort* __restrict__ Zb, const float* __restrict__ H,
    const ushort* __restrict__ preHb, float* __restrict__ out, int N)
{
    int wid = blockIdx.x * 4 + (threadIdx.x >> 6);
    int lane = threadIdx.x & 63;
    int row0 = wid * 32;
    if (row0 >= N) return;

    f32x4 acc[2][4];
    #pragma unroll
    for (int ct = 0; ct < 4; ++ct) {
        int col = ct * 16 + (lane & 15);
        float bh = bhh[col];
        #pragma unroll
        for (int rt = 0; rt < 2; ++rt) acc[rt][ct] = (f32x4){bh, bh, bh, bh};
    }

    const ushort* ins[3] = { HRb, T1, T2 };

    #pragma unroll
    for (int m = 0; m < 3; ++m) {
        #pragma unroll
        for (int kt = 0; kt < 2; ++kt) {
            bf16x8 a0 = ldA(ins[m], 64, row0,      lane, kt, N);
            bf16x8 a1 = ldA(ins[m], 64, row0 + 16, lane, kt, N);
            int mt = 30 + m * 2 + kt;
            #pragma unroll
            for (int ct = 0; ct < 4; ++ct) {
                bf16x8 b8 = ldB(Bp, mt, ct, lane);
                acc[0][ct] = MFMA(a0, b8, acc[0][ct]);
                acc[1][ct] = MFMA(a1, b8, acc[1][ct]);
            }
        }
    }

    #pragma unroll
    for (int rt = 0; rt < 2; ++rt) {
        #pragma unroll
        for (int ct = 0; ct < 4; ++ct) {
            int col = ct * 16 + (lane & 15);
            #pragma unroll
            for (int r = 0; r < 4; ++r) {
                int row = row0 + rt * 16 + ((lane >> 4) << 2) + r;
                if (row < N) {
                    int o = row * CH + col;
                    float pre = acc[rt][ct][r] + bf2f(preHb[o]);
                    float z = bf2f(Zb[o]);
                    float h = H[o];
                    out[o] = z * h + (1.f - z) * tanhf(pre);
                }
            }
        }
    }
}

// ---------------- launch ----------------

extern "C" void kernel_launch(void* const* d_in, const int* in_sizes, int n_in,
                              void* d_out, int out_size, void* d_ws, size_t ws_size,
                              hipStream_t stream) {
    const float* X   = (const float*)d_in[0];
    const int*   ei  = (const int*)d_in[1];
    const float* ew  = (const float*)d_in[2];
    const float* H   = (const float*)d_in[3];
    const float* Wxz = (const float*)d_in[4];
    const float* bxz = (const float*)d_in[5];
    const float* Whz = (const float*)d_in[6];
    const float* bhz = (const float*)d_in[7];
    const float* Wxr = (const float*)d_in[8];
    const float* bxr = (const float*)d_in[9];
    const float* Whr = (const float*)d_in[10];
    const float* bhr = (const float*)d_in[11];
    const float* Wxh = (const float*)d_in[12];
    const float* bxh = (const float*)d_in[13];
    const float* Whh = (const float*)d_in[14];
    const float* bhh = (const float*)d_in[15];

    const int N = in_sizes[0] / CH;
    const int E = in_sizes[2];
    const long long NC = (long long)N * CH;

    const int* srcI = ei;
    const int* dstI = ei + E;

    // ---- workspace layout ----
    char* p = (char*)d_ws;
    auto alloc = [&](size_t bytes) { char* r = p; p += (bytes + 255) & ~(size_t)255; return r; };
    int*    rowptr = (int*)alloc((size_t)(N + 1) * 4);
    int2*   emeta  = (int2*)alloc((size_t)E * 8);
    int*    erank  = (int*)alloc((size_t)E * 4);
    float*  deg    = (float*)alloc((size_t)N * 8);      // deg (N) + cnt (N), contiguous
    int*    cnt    = (int*)(deg + N);
    int*    bsum   = (int*)alloc(256 * 4);
    ushort* Bp     = (ushort*)alloc((size_t)36 * 4 * 64 * 8 * 2);
    ushort* XHb    = (ushort*)alloc((size_t)NC * 2 * 2);   // interleaved X|H [N][128]
    ushort* T1xh   = (ushort*)alloc((size_t)NC * 2 * 2);
    ushort* T2xh   = (ushort*)alloc((size_t)NC * 2 * 2);
    ushort* HRb    = (ushort*)alloc((size_t)NC * 2);       // planar [N][64]
    ushort* T1r    = (ushort*)alloc((size_t)NC * 2);
    ushort* T2r    = (ushort*)alloc((size_t)NC * 2);
    ushort* Zb     = (ushort*)alloc((size_t)NC * 2);
    ushort* preHb  = (ushort*)alloc((size_t)NC * 2);

    const int total4 = (int)(NC / 4);
    const int bE = (E + 255) / 256;
    const int bC = (total4 + 255) / 256;
    const int B  = (N + 2047) / 2048;                    // scan blocks (<=64)
    const int bW = (int)((N * 64 + 255) / 256);          // one wave per node
    const int bW2 = (int)((((N + 1) / 2) * 64 + 255) / 256); // 2 nodes per wave
    const int nW = (N + 31) / 32;
    const int bG = (nW + 3) / 4;

    // fused init: degree+hist+rank | cast | pack
    hipMemsetAsync(deg, 0, (size_t)N * 8, stream);
    k_init<<<bE + bC + 36, 256, 0, stream>>>(srcI, dstI, ew, deg, cnt, erank, E,
                                             (const float4*)X, (const float4*)H, XHb, total4,
                                             Wxz, Whz, Wxr, Whr, Wxh, Whh, Bp, bE, bC);

    // multi-block scan (+ fused rsqrt)
    k_scanA<<<B, 256, 0, stream>>>(cnt, rowptr, bsum, N);
    k_scanB<<<1, 64, 0, stream>>>(bsum, B);
    k_scanC<<<B, 256, 0, stream>>>(rowptr, bsum, deg, N, B);

    // atomic-free CSR scatter
    k_scatter<<<bE, 256, 0, stream>>>(srcI, dstI, ew, deg, rowptr, erank, emeta, E);

    // Chebyshev bases for X and H (fused, interleaved)
    k_prop_dual <<<bW, 256, 0, stream>>>(rowptr, emeta, (const unsigned int*)XHb,
                                         (unsigned int*)T1xh, N);
    k_prop_dual2<<<bW, 256, 0, stream>>>(rowptr, emeta, (const unsigned int*)T1xh,
                                         (const unsigned int*)XHb, (unsigned int*)T2xh, N);

    // Pass A: Z, H*R, preH
    k_gA<<<bG, 256, 0, stream>>>(XHb, T1xh, T2xh, Bp,
                                 bxz, bhz, bxr, bhr, bxh,
                                 H, Zb, HRb, preHb, N);

    // Chebyshev bases for H*R (2 nodes/wave)
    k_prop1<<<bW2, 256, 0, stream>>>(rowptr, emeta, (const unsigned int*)HRb,
                                     (unsigned int*)T1r, N);
    k_prop2<<<bW2, 256, 0, stream>>>(rowptr, emeta, (const unsigned int*)T1r,
                                     (const unsigned int*)HRb, (unsigned int*)T2r, N);

    // Pass B: H_new
    k_gB<<<bG, 256, 0, stream>>>(HRb, T1r, T2r, Bp, bhh, Zb, H, preHb, (float*)d_out, N);
}